// Round 1
// baseline (545.796 us; speedup 1.0000x reference)
//
#include <hip/hip_runtime.h>
#include <hip/hip_fp16.h>

typedef _Float16 f16;
typedef _Float16 f16x8 __attribute__((ext_vector_type(8)));
typedef _Float16 f16x4 __attribute__((ext_vector_type(4)));
typedef float f32x4 __attribute__((ext_vector_type(4)));

#define QQ 36864
#define NQB 16   // queries per block
#define MT 64    // rows per block = NQB*4

// Shared k-slot permutation for MFMA A/B fragments (16x16x32):
// consistency between A and B is all that matters for correctness.
__device__ __forceinline__ int kslot(int g, int i) {
    return 4*g + (i & 3) + ((i >> 2) << 4);
}

// feat (B,C,H,W) f32 -> featT (B,H,W,C) f16
__global__ void transpose_feat_k(const float* __restrict__ feat, f16* __restrict__ featT) {
    int idx = blockIdx.x * 256 + threadIdx.x;   // over B*H*W*C, c fastest
    int c = idx & 63;
    int rest = idx >> 6;
    int x = rest & 63;
    int y = (rest >> 6) & 63;
    int b = rest >> 12;
    featT[idx] = (f16)feat[((b*64 + c)*64 + y)*64 + x];
}

// Pack W (K_real x 256, row-major f32) into fragment order:
// dst[ks][nb][lane][i] = W[refrow(ks*32 + kslot(lane>>4,i))][nb*16 + (lane&15)]
// perm!=0 applies the unfold reorder: our k' = k9*64 + c  ->  ref k = c*9 + k9
__global__ void pack_w_k(const float* __restrict__ w, f16* __restrict__ dst,
                         int nks, int kreal, int perm) {
    int e = blockIdx.x * 256 + threadIdx.x;
    if (e >= nks * 8192) return;
    int i = e & 7, lane = (e >> 3) & 63, nb = (e >> 9) & 15, ks = e >> 13;
    int k = ks*32 + kslot(lane >> 4, i);
    int n = nb*16 + (lane & 15);
    float v = 0.f;
    if (k < kreal) {
        int rk = k;
        if (perm && k < 576) rk = (k & 63)*9 + (k >> 6);
        v = w[rk*256 + n];
    }
    dst[e] = (f16)v;
}

__global__ __launch_bounds__(512, 4)
void liif_main_k(const f16* __restrict__ featT,
                 const f16* __restrict__ pw0, const f16* __restrict__ pw1,
                 const f16* __restrict__ pw2, const f16* __restrict__ pw3,
                 const float* __restrict__ coord, const float* __restrict__ cell,
                 const float* __restrict__ b0, const float* __restrict__ b1,
                 const float* __restrict__ b2, const float* __restrict__ b3,
                 const float* __restrict__ w4, const float* __restrict__ b4,
                 float* __restrict__ out)
{
    __shared__ f16 Hs[64][264];        // hidden activations, reused across layers
    __shared__ f16 Xs[2][64][80];      // double-buffered layer-0 K-chunk (64 k' each)
    __shared__ int   iys[64], ixs[64];
    __shared__ float relxs[64], relys[64], cxs[64], cys[64], areas[64];
    __shared__ float predb[64][3];
    __shared__ float ws4[771];         // w4 (768) + b4 (3)

    const int t   = threadIdx.x;
    const int blk = blockIdx.x;
    const int b   = blk / (QQ / NQB);
    const int qt  = blk % (QQ / NQB);

    // ---------------- phase 0: per-row meta ----------------
    if (t < 64) {
        const int r = t, ql = r >> 2, s = r & 3;
        const int q = qt * NQB + ql;
        const float c0  = coord[(b*QQ + q)*2 + 0];
        const float c1  = coord[(b*QQ + q)*2 + 1];
        const float ce0 = cell[(b*QQ + q)*2 + 0] * 64.f;
        const float ce1 = cell[(b*QQ + q)*2 + 1] * 64.f;
        const float vx = (s & 2) ? 1.f : -1.f;
        const float vy = (s & 1) ? 1.f : -1.f;
        float cx = c0 + vx*(1.f/64.f) + 1e-6f;
        cx = fminf(fmaxf(cx, -1.f + 1e-6f), 1.f - 1e-6f);
        float cy = c1 + vy*(1.f/64.f) + 1e-6f;
        cy = fminf(fmaxf(cy, -1.f + 1e-6f), 1.f - 1e-6f);
        float fiy = floorf(((cx + 1.f)*64.f - 1.f)*0.5f + 0.5f);
        fiy = fminf(fmaxf(fiy, 0.f), 63.f);
        float fix = floorf(((cy + 1.f)*64.f - 1.f)*0.5f + 0.5f);
        fix = fminf(fmaxf(fix, 0.f), 63.f);
        const float qcx = (fiy + 0.5f)*(2.f/64.f) - 1.f;
        const float qcy = (fix + 0.5f)*(2.f/64.f) - 1.f;
        const float rx = (c0 - qcx)*64.f;
        const float ry = (c1 - qcy)*64.f;
        iys[r] = (int)fiy; ixs[r] = (int)fix;
        relxs[r] = rx; relys[r] = ry;
        cxs[r] = ce0;  cys[r] = ce1;
        areas[r] = fabsf(rx*ry) + 1e-9f;
    }
    for (int idx = t; idx < 771; idx += 512)
        ws4[idx] = (idx < 768) ? w4[idx] : b4[idx - 768];
    __syncthreads();

    const int lane = t & 63;
    const int wv = t >> 6;                 // wave 0..7
    const int wm = wv >> 2, wn = wv & 3;   // 2x4 wave grid over M x N
    const int m0 = wm * 32;
    const int l15 = lane & 15, g = lane >> 4;

    // stage one 64-k' chunk of X into Xs[bufi]
    auto stage = [&](int kc, int bufi) {
        const int r  = t >> 3;
        const int cg = (t & 7) * 8;
        if (kc < 9) {                       // k9 = kc, channels cg..cg+7
            const int kh = kc / 3, kw = kc % 3;
            const int yy = iys[r] + kh - 1;
            const int xx = ixs[r] + kw - 1;
            f16x8 v;
            if (yy >= 0 && yy < 64 && xx >= 0 && xx < 64) {
                v = *(const f16x8*)&featT[(((b*64 + yy)*64 + xx)*64) + cg];
            } else {
                #pragma unroll
                for (int u = 0; u < 8; ++u) v[u] = (f16)0.f;
            }
            *(f16x8*)&Xs[bufi][r][cg] = v;
        } else {                            // tail: rel_x, rel_y, cellx, celly, zeros
            if (cg < 32) {
                f16x8 v;
                #pragma unroll
                for (int u = 0; u < 8; ++u) v[u] = (f16)0.f;
                if (cg == 0) {
                    v[0] = (f16)relxs[r]; v[1] = (f16)relys[r];
                    v[2] = (f16)cxs[r];   v[3] = (f16)cys[r];
                }
                *(f16x8*)&Xs[bufi][r][cg] = v;
            }
        }
    };

    f32x4 acc[2][4];
    #pragma unroll
    for (int mf = 0; mf < 2; ++mf)
        #pragma unroll
        for (int nf = 0; nf < 4; ++nf)
            acc[mf][nf] = (f32x4){0.f, 0.f, 0.f, 0.f};

    // ---------------- layer 0: K = 608 (9 feature chunks + tail) ----------------
    stage(0, 0);
    __syncthreads();
    for (int kc = 0; kc < 10; ++kc) {
        if (kc < 9) stage(kc + 1, (kc + 1) & 1);
        const int nks = (kc < 9) ? 2 : 1;
        for (int j = 0; j < nks; ++j) {
            const int ks = kc*2 + j;
            f16x8 af[2];
            #pragma unroll
            for (int mf = 0; mf < 2; ++mf) {
                const f16* ab = &Xs[kc & 1][m0 + mf*16 + l15][j*32 + 4*g];
                f16x4 lo = *(const f16x4*)ab;
                f16x4 hi = *(const f16x4*)(ab + 16);
                af[mf] = (f16x8){lo[0],lo[1],lo[2],lo[3],hi[0],hi[1],hi[2],hi[3]};
            }
            #pragma unroll
            for (int nf = 0; nf < 4; ++nf) {
                f16x8 bf = *(const f16x8*)&pw0[((ks*16 + (wn*4 + nf))*64 + lane)*8];
                acc[0][nf] = __builtin_amdgcn_mfma_f32_16x16x32_f16(af[0], bf, acc[0][nf], 0, 0, 0);
                acc[1][nf] = __builtin_amdgcn_mfma_f32_16x16x32_f16(af[1], bf, acc[1][nf], 0, 0, 0);
            }
        }
        __syncthreads();
    }

    // bias + relu + write to Hs (C/D: col = lane&15, row = 4*(lane>>4)+reg)
    auto writeback = [&](const float* __restrict__ bias) {
        #pragma unroll
        for (int nf = 0; nf < 4; ++nf) {
            const int n = wn*64 + nf*16 + l15;
            const float bv = bias[n];
            #pragma unroll
            for (int mf = 0; mf < 2; ++mf)
                #pragma unroll
                for (int r4 = 0; r4 < 4; ++r4) {
                    float v = acc[mf][nf][r4] + bv;
                    v = fmaxf(v, 0.f);
                    Hs[m0 + mf*16 + g*4 + r4][n] = (f16)v;
                }
        }
    };

    writeback(b0);
    __syncthreads();

    // ---------------- layers 1..3: K = 256 ----------------
    const f16* const pws[3] = {pw1, pw2, pw3};
    const float* const bss[3] = {b1, b2, b3};
    for (int L = 0; L < 3; ++L) {
        #pragma unroll
        for (int mf = 0; mf < 2; ++mf)
            #pragma unroll
            for (int nf = 0; nf < 4; ++nf)
                acc[mf][nf] = (f32x4){0.f, 0.f, 0.f, 0.f};
        const f16* pw = pws[L];
        for (int ks = 0; ks < 8; ++ks) {
            f16x8 af[2];
            #pragma unroll
            for (int mf = 0; mf < 2; ++mf) {
                const f16* ab = &Hs[m0 + mf*16 + l15][ks*32 + 4*g];
                f16x4 lo = *(const f16x4*)ab;
                f16x4 hi = *(const f16x4*)(ab + 16);
                af[mf] = (f16x8){lo[0],lo[1],lo[2],lo[3],hi[0],hi[1],hi[2],hi[3]};
            }
            #pragma unroll
            for (int nf = 0; nf < 4; ++nf) {
                f16x8 bf = *(const f16x8*)&pw[((ks*16 + (wn*4 + nf))*64 + lane)*8];
                acc[0][nf] = __builtin_amdgcn_mfma_f32_16x16x32_f16(af[0], bf, acc[0][nf], 0, 0, 0);
                acc[1][nf] = __builtin_amdgcn_mfma_f32_16x16x32_f16(af[1], bf, acc[1][nf], 0, 0, 0);
            }
        }
        __syncthreads();      // all reads of Hs done before overwrite
        writeback(bss[L]);
        __syncthreads();
    }

    // ---------------- layer 4 (256 -> 3) + area blend ----------------
    if (t < 192) {
        const int r = t / 3, jj = t % 3;
        float accp = ws4[768 + jj];
        for (int k0 = 0; k0 < 256; k0 += 8) {
            f16x8 hv = *(const f16x8*)&Hs[r][k0];
            #pragma unroll
            for (int u = 0; u < 8; ++u)
                accp += (float)hv[u] * ws4[(k0 + u)*3 + jj];
        }
        predb[r][jj] = accp;
    }
    __syncthreads();
    if (t < 48) {
        const int ql = t / 3, jj = t % 3;
        const int r0 = ql * 4;
        const float tot = areas[r0] + areas[r0+1] + areas[r0+2] + areas[r0+3];
        float val = 0.f;
        #pragma unroll
        for (int s = 0; s < 4; ++s)
            val += predb[r0 + s][jj] * areas[r0 + 3 - s];   // local_ensemble swap
        out[(b*QQ + qt*NQB + ql)*3 + jj] = val / tot;
    }
}

extern "C" void kernel_launch(void* const* d_in, const int* in_sizes, int n_in,
                              void* d_out, int out_size, void* d_ws, size_t ws_size,
                              hipStream_t stream) {
    const float* feat  = (const float*)d_in[0];
    const float* coord = (const float*)d_in[1];
    const float* cell  = (const float*)d_in[2];
    const float* w0 = (const float*)d_in[3];
    const float* b0 = (const float*)d_in[4];
    const float* w1 = (const float*)d_in[5];
    const float* b1 = (const float*)d_in[6];
    const float* w2 = (const float*)d_in[7];
    const float* b2 = (const float*)d_in[8];
    const float* w3 = (const float*)d_in[9];
    const float* b3 = (const float*)d_in[10];
    const float* w4 = (const float*)d_in[11];
    const float* b4 = (const float*)d_in[12];
    float* out = (float*)d_out;

    f16* featT = (f16*)d_ws;                 // 4*64*64*64 halves = 2 MB
    f16* pw0 = featT + 4*64*64*64;           // 19*8192 halves
    f16* pw1 = pw0 + 19*8192;                // 8*8192 halves each
    f16* pw2 = pw1 + 8*8192;
    f16* pw3 = pw2 + 8*8192;

    transpose_feat_k<<<4096, 256, 0, stream>>>(feat, featT);
    pack_w_k<<<608, 256, 0, stream>>>(w0, pw0, 19, 580, 1);
    pack_w_k<<<256, 256, 0, stream>>>(w1, pw1, 8, 256, 0);
    pack_w_k<<<256, 256, 0, stream>>>(w2, pw2, 8, 256, 0);
    pack_w_k<<<256, 256, 0, stream>>>(w3, pw3, 8, 256, 0);
    liif_main_k<<<9216, 512, 0, stream>>>(featT, pw0, pw1, pw2, pw3,
                                          coord, cell, b0, b1, b2, b3,
                                          w4, b4, out);
}